// Round 6
// baseline (565.713 us; speedup 1.0000x reference)
//
#include <hip/hip_runtime.h>
#include <hip/hip_bf16.h>

typedef _Float16 half8 __attribute__((ext_vector_type(8)));
typedef _Float16 half2t __attribute__((ext_vector_type(2)));
typedef float f32x4 __attribute__((ext_vector_type(4)));

#define B_SZ 64
#define T_SZ 512
#define E_SZ 768
#define H_SZ 256
#define V_SZ 3072

// workspace layout (bytes)
#define WS_X     0u          // _Float16 x[T][B][H]           16,777,216 B
#define WS_WT    16777216u   // _Float16 Wt[256][768] (Wxh^T)    393,216 B
#define WS_WP    17170432u   // uint     Wp[256][128] ([j][k])   131,072 B
#define WS_H     17301504u   // float    h[64][256]               65,536 B

static __device__ __forceinline__ float dot2p(int hp, unsigned int wp, float c) {
#if defined(__has_builtin) && __has_builtin(__builtin_amdgcn_fdot2)
  return __builtin_amdgcn_fdot2(__builtin_bit_cast(half2t, hp),
                                __builtin_bit_cast(half2t, wp), c, false);
#else
  half2t a = __builtin_bit_cast(half2t, hp);
  half2t b = __builtin_bit_cast(half2t, wp);
  return c + (float)a[0]*(float)b[0] + (float)a[1]*(float)b[1];
#endif
}

// fast tanh: 1 - 2/(1+exp(2x)); exact at +/-inf, ~1e-6 rel err
static __device__ __forceinline__ float fast_tanh(float x) {
  float e = __builtin_amdgcn_exp2f(x * 2.8853900817779268f); // exp(2x)
  return 1.0f - 2.0f * __builtin_amdgcn_rcpf(1.0f + e);
}

// ---------------- k0: prep f16 weight layouts (small) ----------------
__global__ __launch_bounds__(256) void k0_convert(
    const float* __restrict__ Wxh,
    const float* __restrict__ Whh,
    _Float16* __restrict__ Wt,
    unsigned int* __restrict__ Wp)
{
  int gid = blockIdx.x * 256 + threadIdx.x;           // grid = 768 WGs = 196608
  if (gid < E_SZ * H_SZ) {                            // Wxh[e][h] -> Wt[h][e]
    int e = gid >> 8, h = gid & 255;
    Wt[h * E_SZ + e] = (_Float16)Wxh[gid];
  }
  if (gid < 128 * H_SZ) {                             // pack Whh pairs, layout [j][k]
    int k = gid >> 8, j = gid & 255;                  // pair k = rows 2k,2k+1, col j
    _Float16 lo = (_Float16)Whh[(2 * k) * H_SZ + j];
    _Float16 hi = (_Float16)Whh[(2 * k + 1) * H_SZ + j];
    unsigned short lu = __builtin_bit_cast(unsigned short, lo);
    unsigned short hu = __builtin_bit_cast(unsigned short, hi);
    Wp[j * 128 + k] = (unsigned int)lu | ((unsigned int)hu << 16);
  }
}

// ---------------- k1: x[t,b,:] = emb[idx[b,t],:] @ Wxh  (MFMA f16) ----------------
// B panels staged in LDS in FRAGMENT ORDER: fragment f=(nt*64+lane) at bp+f*16B,
// so compute-side reads are stride-1 ds_read_b128 (optimal). A read f32 global,
// converted in-register. Both A and B prefetched one ki ahead.
__global__ __launch_bounds__(256) void k1_xproj(
    const int* __restrict__ idx,
    const float* __restrict__ emb,
    const _Float16* __restrict__ Wt,
    _Float16* __restrict__ x)
{
  const int tid  = threadIdx.x;
  const int w    = tid >> 6;
  const int lane = tid & 63;
  const int m16  = lane & 15;
  const int quad = lane >> 4;
  const int r = blockIdx.x * 64 + w * 16 + m16;     // row in [T*B], r = t*64 + b
  const int t = r >> 6;
  const int b = r & 63;
  const int erow = idx[b * T_SZ + t];
  const float* Arow = emb + (size_t)erow * E_SZ + quad * 8;   // A[m][k=quad*8+j]

  __shared__ __align__(16) _Float16 bp[16 * 64 * 8]; // 16KB: fragment-ordered B panel
  // stager: this thread writes fragments f = tid + 256*pp, pp=0..3
  int n_[4], kb_[4];
#pragma unroll
  for (int pp = 0; pp < 4; ++pp) {
    int f = tid + 256 * pp;
    n_[pp]  = ((f >> 6) << 4) | (f & 15);   // output col of this fragment
    kb_[pp] = (f >> 4) & 3;                 // quad (k sub-block)
  }
  uint4 stg[4];
#pragma unroll
  for (int pp = 0; pp < 4; ++pp)
    stg[pp] = *(const uint4*)(Wt + (size_t)n_[pp] * E_SZ + kb_[pp] * 8);
  f32x4 af0 = *(const f32x4*)(Arow);
  f32x4 af1 = *(const f32x4*)(Arow + 4);

  f32x4 acc[16];
#pragma unroll
  for (int n = 0; n < 16; ++n) { f32x4 z = {0.f, 0.f, 0.f, 0.f}; acc[n] = z; }

#pragma unroll 1
  for (int ki = 0; ki < 24; ++ki) {
    __syncthreads();                         // previous compute done with bp
#pragma unroll
    for (int pp = 0; pp < 4; ++pp)
      *(uint4*)(bp + (size_t)(tid + 256 * pp) * 8) = stg[pp];
    __syncthreads();
    if (ki < 23) {                           // prefetch next B panel + next A
#pragma unroll
      for (int pp = 0; pp < 4; ++pp)
        stg[pp] = *(const uint4*)(Wt + (size_t)n_[pp] * E_SZ + (ki + 1) * 32 + kb_[pp] * 8);
    }
    f32x4 af0n = af0, af1n = af1;
    if (ki < 23) {
      af0n = *(const f32x4*)(Arow + (ki + 1) * 32);
      af1n = *(const f32x4*)(Arow + (ki + 1) * 32 + 4);
    }
    half8 a;
#pragma unroll
    for (int e = 0; e < 4; ++e) { a[e] = (_Float16)af0[e]; a[4 + e] = (_Float16)af1[e]; }
#pragma unroll
    for (int nt = 0; nt < 16; ++nt) {
      half8 bb = *(const half8*)(bp + (size_t)(nt * 64 + lane) * 8); // stride-1 b128
      acc[nt] = __builtin_amdgcn_mfma_f32_16x16x32_f16(a, bb, acc[nt], 0, 0, 0);
    }
    af0 = af0n; af1 = af1n;
  }
  const int rbase = blockIdx.x * 64 + w * 16 + quad * 4;  // C/D: col=lane&15, row=quad*4+reg
#pragma unroll
  for (int nt = 0; nt < 16; ++nt) {
    const int col = nt * 16 + m16;
#pragma unroll
    for (int rg = 0; rg < 4; ++rg) {
      x[(size_t)(rbase + rg) * H_SZ + col] = (_Float16)acc[nt][rg];
    }
  }
}

// ---------------- k2: the recurrence, one WG per batch ----------------
// Whh column j parked in 128 AGPRs via inline asm ("a" constraints -> compiler
// tracks liveness & agpr_count; volatile -> cannot be remat'd/spilled like the
// VGPR attempts of r2-r5). Per step: 128 accvgpr_read + 128 v_dot2 (pure issue),
// h broadcast via same-address ds_read_b128.
#define DECLW(c) \
  unsigned g##c##x, g##c##y, g##c##z, g##c##w; \
  { uint4 q = Wp4[(size_t)j * 32 + c]; \
    asm volatile("v_accvgpr_write_b32 %0, %1" : "=a"(g##c##x) : "v"(q.x)); \
    asm volatile("v_accvgpr_write_b32 %0, %1" : "=a"(g##c##y) : "v"(q.y)); \
    asm volatile("v_accvgpr_write_b32 %0, %1" : "=a"(g##c##z) : "v"(q.z)); \
    asm volatile("v_accvgpr_write_b32 %0, %1" : "=a"(g##c##w) : "v"(q.w)); }

#define RDDOT(av, hp, acc) do { unsigned t_; \
    asm volatile("v_accvgpr_read_b32 %0, %1" : "=v"(t_) : "a"(av)); \
    acc = dot2p((int)(hp), t_, acc); } while (0)

#define STEPC(c, cn) { uint4 hn = lv[cn]; \
  RDDOT(g##c##x, hc.x, s0); RDDOT(g##c##y, hc.y, s1); \
  RDDOT(g##c##z, hc.z, s2); RDDOT(g##c##w, hc.w, s3); hc = hn; }

#define REP32(M) M(0) M(1) M(2) M(3) M(4) M(5) M(6) M(7) \
  M(8) M(9) M(10) M(11) M(12) M(13) M(14) M(15) \
  M(16) M(17) M(18) M(19) M(20) M(21) M(22) M(23) \
  M(24) M(25) M(26) M(27) M(28) M(29) M(30) M(31)

__global__
__attribute__((amdgpu_flat_work_group_size(256, 256)))
__attribute__((amdgpu_waves_per_eu(1, 1)))
void k2_rnn(
    const unsigned int* __restrict__ Wp,
    const _Float16* __restrict__ x,
    const float* __restrict__ Bh,
    float* __restrict__ hout,
    float* __restrict__ hidout)
{
  const int b = blockIdx.x;
  const int j = threadIdx.x;                 // output column this thread owns
  __shared__ __align__(16) unsigned int lh[2][128]; // packed f16 pairs of h, dbuf
  const uint4* Wp4 = (const uint4*)Wp;
  REP32(DECLW)                               // 128 AGPRs of Whh column j
  const float bhj = Bh[j];
  const _Float16* xp = x + b * H_SZ + j;
  _Float16 xq = xp[0];
  float hval = 0.f;
  if (j < 128) lh[1][j] = 0u;                // iter 0 reads buf1 = zeros
  __syncthreads();
#pragma unroll 1
  for (int t = 0; t < T_SZ; ++t) {
    const int tn = (t < T_SZ - 1) ? (t + 1) : t;
    _Float16 xn = xp[(size_t)tn * (B_SZ * H_SZ)];   // prefetch next step's x
    const uint4* lv = (const uint4*)lh[(t + 1) & 1]; // read buffer (broadcast)
    float s0 = bhj + (float)xq;
    float s1 = 0.f, s2 = 0.f, s3 = 0.f;
    uint4 hc = lv[0];
    STEPC(0,1)  STEPC(1,2)  STEPC(2,3)  STEPC(3,4)
    STEPC(4,5)  STEPC(5,6)  STEPC(6,7)  STEPC(7,8)
    STEPC(8,9)  STEPC(9,10) STEPC(10,11) STEPC(11,12)
    STEPC(12,13) STEPC(13,14) STEPC(14,15) STEPC(15,16)
    STEPC(16,17) STEPC(17,18) STEPC(18,19) STEPC(19,20)
    STEPC(20,21) STEPC(21,22) STEPC(22,23) STEPC(23,24)
    STEPC(24,25) STEPC(25,26) STEPC(26,27) STEPC(27,28)
    STEPC(28,29) STEPC(29,30) STEPC(30,31) STEPC(31,31)
    hval = fast_tanh((s0 + s1) + (s2 + s3));
    _Float16 hh = (_Float16)hval;
    ((unsigned short*)lh[t & 1])[j] = __builtin_bit_cast(unsigned short, hh);
    __syncthreads();
    xq = xn;
  }
  hout[b * H_SZ + j] = hval;
  hidout[b * H_SZ + j] = hval;
}

// ---------------- k3: out = hidden @ Wy + By  (all f32) ----------------
__global__ __launch_bounds__(256) void k3_out(
    const float* __restrict__ h,
    const float* __restrict__ Wy,
    const float* __restrict__ By,
    float* __restrict__ out)
{
  __shared__ float hs[H_SZ];
  const int c = blockIdx.x;   // vocab chunk
  const int b = blockIdx.y;   // batch
  const int v = c * 256 + threadIdx.x;
  hs[threadIdx.x] = h[b * H_SZ + threadIdx.x];
  __syncthreads();
  float acc = By[v];
#pragma unroll 8
  for (int jj = 0; jj < H_SZ; ++jj) {
    acc += hs[jj] * Wy[(size_t)jj * V_SZ + v];
  }
  out[(size_t)b * V_SZ + v] = acc;
}

extern "C" void kernel_launch(void* const* d_in, const int* in_sizes, int n_in,
                              void* d_out, int out_size, void* d_ws, size_t ws_size,
                              hipStream_t stream)
{
  const int*   idx = (const int*)d_in[0];
  const float* emb = (const float*)d_in[1];
  const float* Wxh = (const float*)d_in[2];
  const float* Whh = (const float*)d_in[3];
  const float* Wy  = (const float*)d_in[4];
  const float* By  = (const float*)d_in[5];
  const float* Bh  = (const float*)d_in[6];

  char* ws = (char*)d_ws;
  _Float16*     x    = (_Float16*)(ws + WS_X);
  _Float16*     Wt   = (_Float16*)(ws + WS_WT);
  unsigned int* Wp   = (unsigned int*)(ws + WS_WP);
  float*        hbuf = (float*)(ws + WS_H);

  float* out    = (float*)d_out;
  float* hidout = out + (size_t)B_SZ * V_SZ;

  k0_convert<<<768, 256, 0, stream>>>(Wxh, Whh, Wt, Wp);
  k1_xproj  <<<512, 256, 0, stream>>>(idx, emb, Wt, x);
  k2_rnn    <<<64, 256, 0, stream>>>(Wp, x, Bh, hbuf, hidout);
  k3_out    <<<dim3(12, 64), 256, 0, stream>>>(hbuf, Wy, By, out);
}

// Round 7
// 403.023 us; speedup vs baseline: 1.4037x; 1.4037x over previous
//
#include <hip/hip_runtime.h>
#include <hip/hip_bf16.h>

typedef _Float16 half8 __attribute__((ext_vector_type(8)));
typedef float f32x4 __attribute__((ext_vector_type(4)));

#define B_SZ 64
#define T_SZ 512
#define E_SZ 768
#define H_SZ 256
#define V_SZ 3072

// workspace layout (bytes)
#define WS_X     0u          // _Float16 x[T][B][H]           16,777,216 B
#define WS_WT    16777216u   // _Float16 Wt[256][768] (Wxh^T)    393,216 B
#define WS_WF    17170432u   // _Float16 Wf[65536] Whh MFMA-B    131,072 B
#define WS_H     17301504u   // float    h[64][256]               65,536 B

// fast tanh: 1 - 2/(1+exp(2x)); exact at +/-inf, ~1e-6 rel err
static __device__ __forceinline__ float fast_tanh(float x) {
  float e = __builtin_amdgcn_exp2f(x * 2.8853900817779268f); // exp(2x)
  return 1.0f - 2.0f * __builtin_amdgcn_rcpf(1.0f + e);
}

// ---------------- k0: prep f16 weight layouts (small) ----------------
// Wt[h][e] = Wxh[e][h] (for k1's B fragments).
// Wf = Whh in MFMA-B fragment order (same convention as k1's validated bp):
//   frag(nt,kt)[lane][j] = Whh[kt*32 + (lane>>4)*8 + j][nt*16 + (lane&15)]
//   flat = ((nt*8+kt)*64+lane)*8 + j
__global__ __launch_bounds__(256) void k0_convert(
    const float* __restrict__ Wxh,
    const float* __restrict__ Whh,
    _Float16* __restrict__ Wt,
    _Float16* __restrict__ Wf)
{
  int gid = blockIdx.x * 256 + threadIdx.x;           // 768 WGs = 196608
  if (gid < E_SZ * H_SZ) {
    int e = gid >> 8, h = gid & 255;
    Wt[h * E_SZ + e] = (_Float16)Wxh[gid];
  }
  if (gid < 65536) {
    int j = gid & 7, lane = (gid >> 3) & 63, kt = (gid >> 9) & 7, nt = gid >> 12;
    int quad = lane >> 4, n16 = lane & 15;
    int row = kt * 32 + quad * 8 + j, col = nt * 16 + n16;
    Wf[gid] = (_Float16)Whh[row * H_SZ + col];
  }
}

// ---------------- k1: x[t,b,:] = emb[idx[b,t],:] @ Wxh  (MFMA f16) ----------------
__global__ __launch_bounds__(256) void k1_xproj(
    const int* __restrict__ idx,
    const float* __restrict__ emb,
    const _Float16* __restrict__ Wt,
    _Float16* __restrict__ x)
{
  const int tid  = threadIdx.x;
  const int w    = tid >> 6;
  const int lane = tid & 63;
  const int m16  = lane & 15;
  const int quad = lane >> 4;
  const int r = blockIdx.x * 64 + w * 16 + m16;     // row in [T*B], r = t*64 + b
  const int t = r >> 6;
  const int b = r & 63;
  const int erow = idx[b * T_SZ + t];
  const float* Arow = emb + (size_t)erow * E_SZ + quad * 8;   // A[m][k=quad*8+j]

  __shared__ __align__(16) _Float16 bp[16 * 64 * 8]; // 16KB fragment-ordered B panel
  int n_[4], kb_[4];
#pragma unroll
  for (int pp = 0; pp < 4; ++pp) {
    int f = tid + 256 * pp;
    n_[pp]  = ((f >> 6) << 4) | (f & 15);
    kb_[pp] = (f >> 4) & 3;
  }
  uint4 stg[4];
#pragma unroll
  for (int pp = 0; pp < 4; ++pp)
    stg[pp] = *(const uint4*)(Wt + (size_t)n_[pp] * E_SZ + kb_[pp] * 8);
  f32x4 af0 = *(const f32x4*)(Arow);
  f32x4 af1 = *(const f32x4*)(Arow + 4);

  f32x4 acc[16];
#pragma unroll
  for (int n = 0; n < 16; ++n) { f32x4 z = {0.f, 0.f, 0.f, 0.f}; acc[n] = z; }

#pragma unroll 1
  for (int ki = 0; ki < 24; ++ki) {
    __syncthreads();
#pragma unroll
    for (int pp = 0; pp < 4; ++pp)
      *(uint4*)(bp + (size_t)(tid + 256 * pp) * 8) = stg[pp];
    __syncthreads();
    if (ki < 23) {
#pragma unroll
      for (int pp = 0; pp < 4; ++pp)
        stg[pp] = *(const uint4*)(Wt + (size_t)n_[pp] * E_SZ + (ki + 1) * 32 + kb_[pp] * 8);
    }
    f32x4 af0n = af0, af1n = af1;
    if (ki < 23) {
      af0n = *(const f32x4*)(Arow + (ki + 1) * 32);
      af1n = *(const f32x4*)(Arow + (ki + 1) * 32 + 4);
    }
    half8 a;
#pragma unroll
    for (int e = 0; e < 4; ++e) { a[e] = (_Float16)af0[e]; a[4 + e] = (_Float16)af1[e]; }
#pragma unroll
    for (int nt = 0; nt < 16; ++nt) {
      half8 bb = *(const half8*)(bp + (size_t)(nt * 64 + lane) * 8);
      acc[nt] = __builtin_amdgcn_mfma_f32_16x16x32_f16(a, bb, acc[nt], 0, 0, 0);
    }
    af0 = af0n; af1 = af1n;
  }
  const int rbase = blockIdx.x * 64 + w * 16 + quad * 4;  // C/D: col=lane&15, row=quad*4+reg
#pragma unroll
  for (int nt = 0; nt < 16; ++nt) {
    const int col = nt * 16 + m16;
#pragma unroll
    for (int rg = 0; rg < 4; ++rg) {
      x[(size_t)(rbase + rg) * H_SZ + col] = (_Float16)acc[nt][rg];
    }
  }
}

// ---------------- k2: recurrence via MFMA, B-fragments parked in a0..a127 ----
// Wave w owns N-tiles nt=w*4+c (c=0..3); for each of 8 K-tiles a fragment sits
// at AGPRs a[(c*8+kt)*4 .. +3], written once at init. A-operand = h replicated
// over rows (quad-broadcast ds_read_b128). One asm block per step holds the 32
// MFMAs + trailing s_nop pair so consumers are ordered after the wait-states.
#define LDFRAG(C, KT, R0, R1, R2, R3) { \
  uint4 q = Wf4[(((size_t)(w * 4 + C) * 8 + KT) * 64) + lane]; \
  asm volatile("v_accvgpr_write_b32 a" #R0 ", %0" :: "v"(q.x) : "a" #R0); \
  asm volatile("v_accvgpr_write_b32 a" #R1 ", %0" :: "v"(q.y) : "a" #R1); \
  asm volatile("v_accvgpr_write_b32 a" #R2 ", %0" :: "v"(q.z) : "a" #R2); \
  asm volatile("v_accvgpr_write_b32 a" #R3 ", %0" :: "v"(q.w) : "a" #R3); }

__global__ __launch_bounds__(256) void k2_rnn(
    const _Float16* __restrict__ Wf,
    const _Float16* __restrict__ x,
    const float* __restrict__ Bh,
    float* __restrict__ hout,
    float* __restrict__ hidout)
{
  const int b    = blockIdx.x;
  const int tid  = threadIdx.x;
  const int w    = tid >> 6;
  const int lane = tid & 63;
  const int quad = lane >> 4;
  __shared__ __align__(16) _Float16 hb[2][H_SZ];   // h as f16, double-buffered
  const uint4* Wf4 = (const uint4*)Wf;

  LDFRAG(0,0,  0,  1,  2,  3)  LDFRAG(0,1,  4,  5,  6,  7)
  LDFRAG(0,2,  8,  9, 10, 11)  LDFRAG(0,3, 12, 13, 14, 15)
  LDFRAG(0,4, 16, 17, 18, 19)  LDFRAG(0,5, 20, 21, 22, 23)
  LDFRAG(0,6, 24, 25, 26, 27)  LDFRAG(0,7, 28, 29, 30, 31)
  LDFRAG(1,0, 32, 33, 34, 35)  LDFRAG(1,1, 36, 37, 38, 39)
  LDFRAG(1,2, 40, 41, 42, 43)  LDFRAG(1,3, 44, 45, 46, 47)
  LDFRAG(1,4, 48, 49, 50, 51)  LDFRAG(1,5, 52, 53, 54, 55)
  LDFRAG(1,6, 56, 57, 58, 59)  LDFRAG(1,7, 60, 61, 62, 63)
  LDFRAG(2,0, 64, 65, 66, 67)  LDFRAG(2,1, 68, 69, 70, 71)
  LDFRAG(2,2, 72, 73, 74, 75)  LDFRAG(2,3, 76, 77, 78, 79)
  LDFRAG(2,4, 80, 81, 82, 83)  LDFRAG(2,5, 84, 85, 86, 87)
  LDFRAG(2,6, 88, 89, 90, 91)  LDFRAG(2,7, 92, 93, 94, 95)
  LDFRAG(3,0, 96, 97, 98, 99)  LDFRAG(3,1,100,101,102,103)
  LDFRAG(3,2,104,105,106,107)  LDFRAG(3,3,108,109,110,111)
  LDFRAG(3,4,112,113,114,115)  LDFRAG(3,5,116,117,118,119)
  LDFRAG(3,6,120,121,122,123)  LDFRAG(3,7,124,125,126,127)

  const float bhj = Bh[tid];
  const _Float16* xp = x + b * H_SZ + tid;
  _Float16 xq = xp[0];
  f32x4 zero4 = {0.f, 0.f, 0.f, 0.f};
  asm volatile("" : "+v"(zero4));        // pin: no remat-mov adjacent to MFMA srcC
  hb[1][tid] = (_Float16)0.f;            // t=0 reads buffer 1 = zeros
  float hval = 0.f;
  __syncthreads();

#pragma unroll 1
  for (int t = 0; t < T_SZ; ++t) {
    const int tn = (t < T_SZ - 1) ? (t + 1) : t;
    _Float16 xn = xp[(size_t)tn * (B_SZ * H_SZ)];   // prefetch next x
    const _Float16* hr = hb[(t + 1) & 1];
    // A fragments: h[kt*32+quad*8 .. +7], same for all 16 rows (quad-broadcast)
    half8 va0 = *(const half8*)(hr +   0 + quad * 8);
    half8 va1 = *(const half8*)(hr +  32 + quad * 8);
    half8 va2 = *(const half8*)(hr +  64 + quad * 8);
    half8 va3 = *(const half8*)(hr +  96 + quad * 8);
    half8 va4 = *(const half8*)(hr + 128 + quad * 8);
    half8 va5 = *(const half8*)(hr + 160 + quad * 8);
    half8 va6 = *(const half8*)(hr + 192 + quad * 8);
    half8 va7 = *(const half8*)(hr + 224 + quad * 8);
    f32x4 acc0, acc1, acc2, acc3;
    asm volatile(
      "v_mfma_f32_16x16x32_f16 %[t0], %[a0], a[0:3], %[z]\n\t"
      "v_mfma_f32_16x16x32_f16 %[t1], %[a0], a[32:35], %[z]\n\t"
      "v_mfma_f32_16x16x32_f16 %[t2], %[a0], a[64:67], %[z]\n\t"
      "v_mfma_f32_16x16x32_f16 %[t3], %[a0], a[96:99], %[z]\n\t"
      "v_mfma_f32_16x16x32_f16 %[t0], %[a1], a[4:7], %[t0]\n\t"
      "v_mfma_f32_16x16x32_f16 %[t1], %[a1], a[36:39], %[t1]\n\t"
      "v_mfma_f32_16x16x32_f16 %[t2], %[a1], a[68:71], %[t2]\n\t"
      "v_mfma_f32_16x16x32_f16 %[t3], %[a1], a[100:103], %[t3]\n\t"
      "v_mfma_f32_16x16x32_f16 %[t0], %[a2], a[8:11], %[t0]\n\t"
      "v_mfma_f32_16x16x32_f16 %[t1], %[a2], a[40:43], %[t1]\n\t"
      "v_mfma_f32_16x16x32_f16 %[t2], %[a2], a[72:75], %[t2]\n\t"
      "v_mfma_f32_16x16x32_f16 %[t3], %[a2], a[104:107], %[t3]\n\t"
      "v_mfma_f32_16x16x32_f16 %[t0], %[a3], a[12:15], %[t0]\n\t"
      "v_mfma_f32_16x16x32_f16 %[t1], %[a3], a[44:47], %[t1]\n\t"
      "v_mfma_f32_16x16x32_f16 %[t2], %[a3], a[76:79], %[t2]\n\t"
      "v_mfma_f32_16x16x32_f16 %[t3], %[a3], a[108:111], %[t3]\n\t"
      "v_mfma_f32_16x16x32_f16 %[t0], %[a4], a[16:19], %[t0]\n\t"
      "v_mfma_f32_16x16x32_f16 %[t1], %[a4], a[48:51], %[t1]\n\t"
      "v_mfma_f32_16x16x32_f16 %[t2], %[a4], a[80:83], %[t2]\n\t"
      "v_mfma_f32_16x16x32_f16 %[t3], %[a4], a[112:115], %[t3]\n\t"
      "v_mfma_f32_16x16x32_f16 %[t0], %[a5], a[20:23], %[t0]\n\t"
      "v_mfma_f32_16x16x32_f16 %[t1], %[a5], a[52:55], %[t1]\n\t"
      "v_mfma_f32_16x16x32_f16 %[t2], %[a5], a[84:87], %[t2]\n\t"
      "v_mfma_f32_16x16x32_f16 %[t3], %[a5], a[116:119], %[t3]\n\t"
      "v_mfma_f32_16x16x32_f16 %[t0], %[a6], a[24:27], %[t0]\n\t"
      "v_mfma_f32_16x16x32_f16 %[t1], %[a6], a[56:59], %[t1]\n\t"
      "v_mfma_f32_16x16x32_f16 %[t2], %[a6], a[88:91], %[t2]\n\t"
      "v_mfma_f32_16x16x32_f16 %[t3], %[a6], a[120:123], %[t3]\n\t"
      "v_mfma_f32_16x16x32_f16 %[t0], %[a7], a[28:31], %[t0]\n\t"
      "v_mfma_f32_16x16x32_f16 %[t1], %[a7], a[60:63], %[t1]\n\t"
      "v_mfma_f32_16x16x32_f16 %[t2], %[a7], a[92:95], %[t2]\n\t"
      "v_mfma_f32_16x16x32_f16 %[t3], %[a7], a[124:127], %[t3]\n\t"
      "s_nop 7\n\t"
      "s_nop 7"
      : [t0] "=&v"(acc0), [t1] "=&v"(acc1), [t2] "=&v"(acc2), [t3] "=&v"(acc3)
      : [a0] "v"(va0), [a1] "v"(va1), [a2] "v"(va2), [a3] "v"(va3),
        [a4] "v"(va4), [a5] "v"(va5), [a6] "v"(va6), [a7] "v"(va7),
        [z] "v"(zero4));
    // D rows identical (A rows replicated); lane (quad q, n16) takes tile q:
    float v0 = acc0[0], v1 = acc1[0], v2 = acc2[0], v3 = acc3[0];
    float ylo = (quad & 1) ? v1 : v0;
    float yhi = (quad & 1) ? v3 : v2;
    float y   = (quad & 2) ? yhi : ylo;     // y = (h @ Whh)[tid]
    hval = fast_tanh(y + (float)xq + bhj);
    hb[t & 1][tid] = (_Float16)hval;
    __syncthreads();
    xq = xn;
  }
  hout[b * H_SZ + tid] = hval;
  hidout[b * H_SZ + tid] = hval;
}

// ---------------- k3: out = hidden @ Wy + By  (all f32) ----------------
__global__ __launch_bounds__(256) void k3_out(
    const float* __restrict__ h,
    const float* __restrict__ Wy,
    const float* __restrict__ By,
    float* __restrict__ out)
{
  __shared__ float hs[H_SZ];
  const int c = blockIdx.x;   // vocab chunk
  const int b = blockIdx.y;   // batch
  const int v = c * 256 + threadIdx.x;
  hs[threadIdx.x] = h[b * H_SZ + threadIdx.x];
  __syncthreads();
  float acc = By[v];
#pragma unroll 8
  for (int jj = 0; jj < H_SZ; ++jj) {
    acc += hs[jj] * Wy[(size_t)jj * V_SZ + v];
  }
  out[(size_t)b * V_SZ + v] = acc;
}

extern "C" void kernel_launch(void* const* d_in, const int* in_sizes, int n_in,
                              void* d_out, int out_size, void* d_ws, size_t ws_size,
                              hipStream_t stream)
{
  const int*   idx = (const int*)d_in[0];
  const float* emb = (const float*)d_in[1];
  const float* Wxh = (const float*)d_in[2];
  const float* Whh = (const float*)d_in[3];
  const float* Wy  = (const float*)d_in[4];
  const float* By  = (const float*)d_in[5];
  const float* Bh  = (const float*)d_in[6];

  char* ws = (char*)d_ws;
  _Float16* x    = (_Float16*)(ws + WS_X);
  _Float16* Wt   = (_Float16*)(ws + WS_WT);
  _Float16* Wf   = (_Float16*)(ws + WS_WF);
  float*    hbuf = (float*)(ws + WS_H);

  float* out    = (float*)d_out;
  float* hidout = out + (size_t)B_SZ * V_SZ;

  k0_convert<<<768, 256, 0, stream>>>(Wxh, Whh, Wt, Wf);
  k1_xproj  <<<512, 256, 0, stream>>>(idx, emb, Wt, x);
  k2_rnn    <<<64, 256, 0, stream>>>(Wf, x, Bh, hbuf, hidout);
  k3_out    <<<dim3(12, 64), 256, 0, stream>>>(hbuf, Wy, By, out);
}